// Round 4
// baseline (340.775 us; speedup 1.0000x reference)
//
#include <hip/hip_runtime.h>

typedef _Float16 h2 __attribute__((ext_vector_type(2)));
typedef _Float16 h4 __attribute__((ext_vector_type(4)));
typedef _Float16 h8 __attribute__((ext_vector_type(8)));
typedef float f4 __attribute__((ext_vector_type(4)));

#define BB 256
#define II 1152
#define QQ 8
#define JJ 10
#define PP 16

#define BT 16            // b per block
#define IT 8             // i per block
#define NBT (BB / BT)    // 16
#define NIT (II / IT)    // 144
#define XRH 72           // halfs per staged-x b-row (64 + 8 pad)

#define NW (JJ * II * PP * QQ)   // 1474560
#define NX (BB * II * QQ)        // 2359296
#define NS (BB * JJ * PP)        // 40960
#define LOG2E 1.4426950408889634f

// ---------------------------------------------------------------------------
// DPP helpers: f32 16-lane (vv_kernel) and packed-f16 8-lane (pass).
// ---------------------------------------------------------------------------
template <int CTRL>
__device__ __forceinline__ float dpp_add(float v) {
    int s = __builtin_bit_cast(int, v);
    int t = __builtin_amdgcn_update_dpp(0, s, CTRL, 0xF, 0xF, true);
    return v + __builtin_bit_cast(float, t);
}
__device__ __forceinline__ float row_sum16(float v) {
    v = dpp_add<0xB1>(v);   // xor1
    v = dpp_add<0x4E>(v);   // xor2
    v = dpp_add<0x124>(v);  // row_ror:4
    v = dpp_add<0x128>(v);  // row_ror:8
    return v;
}
template <int CTRL>
__device__ __forceinline__ h2 dpp_add_pk(h2 v) {
    int s = __builtin_bit_cast(int, v);
    int t = __builtin_amdgcn_update_dpp(0, s, CTRL, 0xF, 0xF, true);
    return v + __builtin_bit_cast(h2, t);   // v_pk_add_f16
}
// sum over 8-lane groups (q-lanes): xor1, xor2, half_mirror
__device__ __forceinline__ h2 row_sum8_pk(h2 v) {
    v = dpp_add_pk<0xB1>(v);    // quad_perm xor1
    v = dpp_add_pk<0x4E>(v);    // quad_perm xor2
    v = dpp_add_pk<0x141>(v);   // row_half_mirror (combine quads within 8)
    return v;
}

// ---------------------------------------------------------------------------
// prep: W,X fp32 -> f16; zero S0/S1/S2 (contiguous).
// ---------------------------------------------------------------------------
__global__ __launch_bounds__(256) void prep_kernel(
    const float* __restrict__ X, const float* __restrict__ W,
    _Float16* __restrict__ Xh, _Float16* __restrict__ Wh,
    float* __restrict__ S)   // 3*NS floats
{
    const int g = blockIdx.x * 256 + threadIdx.x;
    const int stride = gridDim.x * 256;
    for (int k = g; k < NW / 4; k += stride) {
        const float4 f = ((const float4*)W)[k];
        h4 o = { (_Float16)f.x, (_Float16)f.y, (_Float16)f.z, (_Float16)f.w };
        ((h4*)Wh)[k] = o;
    }
    for (int k = g; k < NX / 4; k += stride) {
        const float4 f = ((const float4*)X)[k];
        h4 o = { (_Float16)f.x, (_Float16)f.y, (_Float16)f.z, (_Float16)f.w };
        ((h4*)Xh)[k] = o;
    }
    const float4 z = {0.f, 0.f, 0.f, 0.f};
    for (int k = g; k < 3 * NS / 4; k += stride) ((float4*)S)[k] = z;
}

// ---------------------------------------------------------------------------
// s0 via MFMA: s0 = 0.1 * GEMM over K=(i,q)=9216.  (unchanged, verified)
// ---------------------------------------------------------------------------
__global__ __launch_bounds__(256) void s0_mfma_kernel(
    const _Float16* __restrict__ Xh, const _Float16* __restrict__ Wh,
    float* __restrict__ S0)
{
    const int wid  = blockIdx.x * 4 + (threadIdx.x >> 6);  // 0..1279
    const int lane = threadIdx.x & 63;
    const int bt  = wid / 80;
    const int rem = wid % 80;
    const int j   = rem >> 3;
    const int kc  = rem & 7;
    const int b0  = bt * 16;
    const int m    = lane & 15;
    const int quad = lane >> 4;
    const int ib   = kc * 144;

    const _Float16* ax = Xh + ((size_t)(b0 + m) * II + ib + quad) * QQ;
    const _Float16* bw = Wh + (((size_t)j * II + ib + quad) * PP + m) * QQ;

    f4 acc = {0.f, 0.f, 0.f, 0.f};
    for (int t = 0; t < 36; ++t) {
        const h8 a = *(const h8*)ax;
        const h8 b = *(const h8*)bw;
        acc = __builtin_amdgcn_mfma_f32_16x16x32_f16(a, b, acc, 0, 0, 0);
        ax += 4 * QQ;
        bw += (size_t)4 * PP * QQ;
    }
#pragma unroll
    for (int r = 0; r < 4; ++r)
        atomicAdd(&S0[((size_t)(b0 + quad * 4 + r) * JJ + j) * PP + m], 0.1f * acc[r]);
}

// ---------------------------------------------------------------------------
// vv_kernel: squash + logit-weight precompute; emits f16 VVh (MFMA A-operand
// of the pass's logit GEMM).
//  MODE 0: v = squash(S);  V0raw = v;  VVh = f16(v * log2e)
//  MODE 1: v = squash(S);  VVh = f16((v + V0raw) * log2e)
// ---------------------------------------------------------------------------
template <int MODE>
__global__ __launch_bounds__(256) void vv_kernel(
    const float* __restrict__ S, float* __restrict__ V0raw,
    _Float16* __restrict__ VVh)
{
    const int idx = blockIdx.x * 256 + threadIdx.x;   // 0..NS-1
    const float s = S[idx];
    const float n2 = row_sum16(s * s);
    const float sc = n2 * __builtin_amdgcn_rcpf(1.0f + n2)
                        * __builtin_amdgcn_rsqf(n2 + 1e-7f);
    const float v = s * sc;
    if (MODE == 0) {
        V0raw[idx] = v;
        VVh[idx] = (_Float16)(v * LOG2E);
    } else {
        VVh[idx] = (_Float16)((v + V0raw[idx]) * LOG2E);
    }
}

// ---------------------------------------------------------------------------
// MFMA routing pass. Per block: 16 b x 8 i; wave w owns i-pair (2 i).
// Phase 1 (per j): U[b,iq] = sum_p vv[b,p] * W[p,iq]   (mfma 16x16x16, K=p)
//                  l[b,i]  = sum_q U[b,iq] * x[b,i,q]  (8-lane packed DPP)
// Phase 2: softmax over j in-register (slots = 4 b-rows x lane's i)
// Phase 3 (per j): S[b,p] += sum_{iq} (c*x)[b,iq] * W[iq,p] (mfma, K=2i*8q)
// Cross-wave reduce in LDS, then one global atomicAdd set (same as baseline).
// W LDS tile wtr[j][tile][p][(i&1)*8+q] serves BOTH GEMMs:
//   G1 B-frag: ds_read_b64_tr_b16 down columns (K=p), per-lane addr
//              base + (lane&15)*8 + (lane>>4)*128  [m156/m162 convention;
//              R3 bug was nn*2 instead of nn*8 here]
//   G2 B-frag: plain ds_read_b64 along rows (K=iq).
// ---------------------------------------------------------------------------
__global__ __launch_bounds__(256, 3) void pass_kernel(
    const float* __restrict__ X,      // [B][I][Q] f32 (for xtr staging)
    const _Float16* __restrict__ Xh,  // [B][I][Q] f16
    const _Float16* __restrict__ Wh,  // [J][I][P][Q] f16
    const _Float16* __restrict__ VVh, // [B][J][P] f16 = v * log2e
    float* __restrict__ Sout)         // [B][J][P] pre-zeroed accumulator
{
    __shared__ _Float16 wtr[JJ * 4 * 256];   // 20 KB  [j][tile][16p][16n]
    __shared__ _Float16 xna[BT * XRH];       // 2.25 KB natural x f16
    __shared__ float    xtr[64 * 20];        // 5 KB   [iq][16b + 4 pad] f32
    __shared__ _Float16 vvs[16 * 168];       // 5.25 KB [b][10j*16p + 8 pad]
    __shared__ float    cs[4][JJ][2][16];    // 5 KB   per-wave c bounce
    __shared__ float    sacc[JJ * 16 * 17];  // 10.6 KB cross-wave reduce (pad 17)

    const int bt = blockIdx.x & (NBT - 1);
    const int it = blockIdx.x >> 4;
    const int b0 = bt * BT;
    const int i0 = it * IT;
    const int tid = threadIdx.x;

    // ---- staging (single barrier) ----
    {
        const size_t jstride = (size_t)II * PP * QQ;
        const _Float16* wsrc = Wh + (size_t)i0 * PP * QQ;
#pragma unroll
        for (int k = 0; k < 5; ++k) {
            const int c = tid + k * 256;      // 0..1279
            const int j = c >> 7;
            const int r = c & 127;            // = i*16 + p
            const int i = r >> 4;
            const int p = r & 15;
            const h8 v = *(const h8*)(wsrc + j * jstride + (size_t)r * 8);
            *(h8*)(wtr + (j * 4 + (i >> 1)) * 256 + p * 16 + (i & 1) * 8) = v;
        }
        if (tid < 128) {
            const int xb = tid >> 3;
            const int xr = tid & 7;
            *(h8*)(xna + xb * XRH + xr * 8) =
                *(const h8*)(Xh + ((size_t)(b0 + xb) * II + i0) * QQ + xr * 8);
        }
        {   // xtr: f32 transposed x [iq][b]
            const int qh = tid & 1;
            const int i  = (tid >> 1) & 7;
            const int b  = tid >> 4;
            const float4 v = *(const float4*)(X + ((size_t)(b0 + b) * II + i0 + i) * QQ + qh * 4);
            const int row = i * 8 + qh * 4;
            xtr[(row + 0) * 20 + b] = v.x;
            xtr[(row + 1) * 20 + b] = v.y;
            xtr[(row + 2) * 20 + b] = v.z;
            xtr[(row + 3) * 20 + b] = v.w;
        }
#pragma unroll
        for (int k = 0; k < 5; ++k) {         // vvs: 1280 h2 chunks
            const int c = tid + k * 256;
            const int b = c / 80;
            const int rem = c - b * 80;
            *(unsigned*)(vvs + b * 168 + rem * 2) =
                *(const unsigned*)(VVh + (size_t)(b0 + b) * JJ * PP + rem * 2);
        }
#pragma unroll
        for (int k = 0; k < 3; ++k) {         // zero sacc (680 f4)
            const int c = tid + k * 256;
            if (c < 680) ((f4*)sacc)[c] = f4{0.f, 0.f, 0.f, 0.f};
        }
    }
    __syncthreads();

    const int lane = tid & 63;
    const int wid  = tid >> 6;       // wave = i-pair tile
    const int nn   = lane & 15;
    const int quad = lane >> 4;
    const f4 zf4 = {0.f, 0.f, 0.f, 0.f};

    // A-frag (vv) preload: A[m=b=nn][k=p=quad*4+e]
    h4 vvA[JJ];
#pragma unroll
    for (int j = 0; j < JJ; ++j)
        vvA[j] = *(const h4*)(vvs + nn * 168 + j * 16 + quad * 4);

    // ---- Phase 1: logits ----
    // xr: x f32 for this lane's (iq)=nn column, 4 b-rows
    const f4 xr = *(const f4*)(xtr + (wid * 16 + nn) * 20 + quad * 4);

    // per-lane tr-read address: column nn of the 4x16 row-major sub-matrix
    // (rows p=quad*4..+3). REQUIRED: base + nn*8 + quad*128 bytes.
    const unsigned trbase =
        (unsigned)(size_t)(const void*)wtr +
        (unsigned)(wid * 512 + quad * 128 + nn * 8);

    // issue all 10 transpose-reads, then one wait (overlapped LDS latency)
    h4 bfrag[JJ];
#pragma unroll
    for (int j = 0; j < JJ; ++j) {
        const unsigned a = trbase + (unsigned)(j * 2048);
        asm volatile("ds_read_b64_tr_b16 %0, %1" : "=v"(bfrag[j]) : "v"(a));
    }
    asm volatile("s_waitcnt lgkmcnt(0)" ::: "memory");
    __builtin_amdgcn_sched_barrier(0);   // rule #18: pin MFMA below the wait

    h2 lj0[JJ], lj1[JJ];
#pragma unroll
    for (int j = 0; j < JJ; ++j) {
        const f4 U = __builtin_amdgcn_mfma_f32_16x16x16f16(vvA[j], bfrag[j], zf4, 0, 0, 0);
        const h2 pk0 = __builtin_bit_cast(h2,
            __builtin_amdgcn_cvt_pkrtz(U[0] * xr[0], U[1] * xr[1]));
        const h2 pk1 = __builtin_bit_cast(h2,
            __builtin_amdgcn_cvt_pkrtz(U[2] * xr[2], U[3] * xr[3]));
        lj0[j] = row_sum8_pk(pk0);   // sum over q (8 lanes)
        lj1[j] = row_sum8_pk(pk1);
    }

    // ---- Phase 2: softmax over j (slots: rows b=quad*4+r, i=nn>>3) ----
    float e0[JJ], e1[JJ], e2[JJ], e3[JJ];
#pragma unroll
    for (int j = 0; j < JJ; ++j) {
        e0[j] = __builtin_amdgcn_exp2f((float)lj0[j].x);
        e1[j] = __builtin_amdgcn_exp2f((float)lj0[j].y);
        e2[j] = __builtin_amdgcn_exp2f((float)lj1[j].x);
        e3[j] = __builtin_amdgcn_exp2f((float)lj1[j].y);
    }
    float a0 = 0.f, a1 = 0.f, a2 = 0.f, a3 = 0.f;
#pragma unroll
    for (int j = 0; j < JJ; ++j) { a0 += e0[j]; a1 += e1[j]; a2 += e2[j]; a3 += e3[j]; }
    const float v0 = __builtin_amdgcn_rcpf(a0);
    const float v1 = __builtin_amdgcn_rcpf(a1);
    const float v2 = __builtin_amdgcn_rcpf(a2);
    const float v3 = __builtin_amdgcn_rcpf(a3);

    if ((lane & 7) == 0) {           // one writer per q-group
        const int ii = nn >> 3;
#pragma unroll
        for (int j = 0; j < JJ; ++j) {
            f4 c4v = { e0[j] * v0, e1[j] * v1, e2[j] * v2, e3[j] * v3 };
            *(f4*)&cs[wid][j][ii][quad * 4] = c4v;
        }
    }

    // ---- Phase 3: S[b,p] += sum_{iq} (c*x)[b,iq] * W[iq,p] ----
    // A[m=b=nn][k=(i,q)]: i = quad>>1 (of wave's pair), q-slice (quad&1)*4
    const h4 xf = *(const h4*)(xna + nn * XRH + (wid * 2 + (quad >> 1)) * 8 + (quad & 1) * 4);
    const h2 xlo = __builtin_shufflevector(xf, xf, 0, 1);
    const h2 xhi = __builtin_shufflevector(xf, xf, 2, 3);
#pragma unroll
    for (int j = 0; j < JJ; ++j) {
        const float c = cs[wid][j][quad >> 1][nn];
        const h2 cc = __builtin_bit_cast(h2, __builtin_amdgcn_cvt_pkrtz(c, c));
        const h2 y0 = cc * xlo;
        const h2 y1 = cc * xhi;
        const h4 y = __builtin_shufflevector(y0, y1, 0, 1, 2, 3);
        // B[k=(i,q)][n=p=nn]: natural-orientation read along wtr row p=nn
        const h4 wf = *(const h4*)(wtr + (j * 4 + wid) * 256 + nn * 16 +
                                   (quad >> 1) * 8 + (quad & 1) * 4);
        const f4 C = __builtin_amdgcn_mfma_f32_16x16x16f16(y, wf, zf4, 0, 0, 0);
#pragma unroll
        for (int r = 0; r < 4; ++r)
            atomicAdd(&sacc[(j * 16 + quad * 4 + r) * 17 + nn], C[r]);
    }
    __syncthreads();

    // ---- flush: one global atomic set per block (same count as baseline) ----
    const int bf = tid >> 4, pf = tid & 15;
#pragma unroll
    for (int j = 0; j < JJ; ++j)
        atomicAdd(&Sout[((size_t)(b0 + bf) * JJ + j) * PP + pf],
                  sacc[(j * 16 + bf) * 17 + pf]);
}

// ---------------------------------------------------------------------------
// final output squash (fp32 precise)
// ---------------------------------------------------------------------------
__global__ __launch_bounds__(256) void squash_out_kernel(const float* __restrict__ S,
                                                         float* __restrict__ V)
{
    const int idx = blockIdx.x * blockDim.x + threadIdx.x;  // (b*J + j)
    if (idx >= BB * JJ) return;
    const float4* sp = (const float4*)(S + idx * PP);
    float4 a = sp[0], b4 = sp[1], c4 = sp[2], d4 = sp[3];
    float s2 = a.x * a.x + a.y * a.y + a.z * a.z + a.w * a.w +
               b4.x * b4.x + b4.y * b4.y + b4.z * b4.z + b4.w * b4.w +
               c4.x * c4.x + c4.y * c4.y + c4.z * c4.z + c4.w * c4.w +
               d4.x * d4.x + d4.y * d4.y + d4.z * d4.z + d4.w * d4.w;
    const float scale = s2 / (1.0f + s2) / sqrtf(s2 + 1e-7f);
    a.x *= scale; a.y *= scale; a.z *= scale; a.w *= scale;
    b4.x *= scale; b4.y *= scale; b4.z *= scale; b4.w *= scale;
    c4.x *= scale; c4.y *= scale; c4.z *= scale; c4.w *= scale;
    d4.x *= scale; d4.y *= scale; d4.z *= scale; d4.w *= scale;
    float4* vp = (float4*)(V + idx * PP);
    vp[0] = a; vp[1] = b4; vp[2] = c4; vp[3] = d4;
}

extern "C" void kernel_launch(void* const* d_in, const int* in_sizes, int n_in,
                              void* d_out, int out_size, void* d_ws, size_t ws_size,
                              hipStream_t stream)
{
    const float* X = (const float*)d_in[0];  // [256][1152][8]
    const float* W = (const float*)d_in[1];  // [10][1152][16][8]
    float* out = (float*)d_out;              // [256][10][16]

    _Float16* Xh = (_Float16*)d_ws;          // NX halfs
    _Float16* Wh = Xh + NX;                  // NW halfs
    float* S0 = (float*)(Wh + NW);           // NS floats
    float* S1 = S0 + NS;
    float* S2 = S1 + NS;
    float* V0raw = S2 + NS;                  // NS floats
    _Float16* VVh1 = (_Float16*)(V0raw + NS);  // NS halfs
    _Float16* VVh2 = VVh1 + NS;                // NS halfs

    const int grid  = NBT * NIT;             // 2304 blocks of 256 threads
    const int vgrid = NS / 256;              // 160 blocks

    prep_kernel<<<1024, 256, 0, stream>>>(X, W, Xh, Wh, S0);
    s0_mfma_kernel<<<320, 256, 0, stream>>>(Xh, Wh, S0);
    vv_kernel<0><<<vgrid, 256, 0, stream>>>(S0, V0raw, VVh1);
    pass_kernel<<<grid, 256, 0, stream>>>(X, Xh, Wh, VVh1, S1);
    vv_kernel<1><<<vgrid, 256, 0, stream>>>(S1, V0raw, VVh2);
    pass_kernel<<<grid, 256, 0, stream>>>(X, Xh, Wh, VVh2, S2);
    squash_out_kernel<<<10, 256, 0, stream>>>(S2, out);
}

// Round 5
// 219.215 us; speedup vs baseline: 1.5545x; 1.5545x over previous
//
#include <hip/hip_runtime.h>

typedef _Float16 h2 __attribute__((ext_vector_type(2)));
typedef _Float16 h8 __attribute__((ext_vector_type(8)));
typedef float f4 __attribute__((ext_vector_type(4)));

#define BB 256
#define II 1152
#define QQ 8
#define JJ 10
#define PP 16

#define BT 16            // b per block
#define IT 8             // i per LDS tile
#define IKT 3            // i-tiles per block (K-loop) -> flush atomics / 3
#define NBT (BB / BT)    // 16
#define NIT (II / IT)    // 144
#define NITG (NIT / IKT) // 48 tile-groups
#define XRH 72           // halfs per staged-x b-row (64 + 8 pad)
#define WTILE (IT * PP * QQ)     // 1024 halfs per j in the LDS W-tile

#define NW (JJ * II * PP * QQ)   // 1474560
#define NX (BB * II * QQ)        // 2359296
#define NS (BB * JJ * PP)        // 40960
#define LOG2E 1.4426950408889634f

// ---------------------------------------------------------------------------
// 16-lane row sum via DPP — f32 (for vv_kernel) and packed-f16 (hot loop).
// ---------------------------------------------------------------------------
template <int CTRL>
__device__ __forceinline__ float dpp_add(float v) {
    int s = __builtin_bit_cast(int, v);
    int t = __builtin_amdgcn_update_dpp(0, s, CTRL, 0xF, 0xF, true);
    return v + __builtin_bit_cast(float, t);
}
__device__ __forceinline__ float row_sum16(float v) {
    v = dpp_add<0xB1>(v);   // xor1
    v = dpp_add<0x4E>(v);   // xor2
    v = dpp_add<0x124>(v);  // row_ror:4
    v = dpp_add<0x128>(v);  // row_ror:8
    return v;
}
template <int CTRL>
__device__ __forceinline__ h2 dpp_add_pk(h2 v) {
    int s = __builtin_bit_cast(int, v);
    int t = __builtin_amdgcn_update_dpp(0, s, CTRL, 0xF, 0xF, true);
    return v + __builtin_bit_cast(h2, t);   // v_pk_add_f16
}
__device__ __forceinline__ h2 row_sum16_pk(h2 v) {
    v = dpp_add_pk<0xB1>(v);
    v = dpp_add_pk<0x4E>(v);
    v = dpp_add_pk<0x124>(v);
    v = dpp_add_pk<0x128>(v);
    return v;
}

// 8-element f16 dot with fp32 accumulate: 4 x v_dot2_f32_f16.
__device__ __forceinline__ float dot8(h8 w, h8 x) {
    h2 w0 = __builtin_shufflevector(w, w, 0, 1), w1 = __builtin_shufflevector(w, w, 2, 3);
    h2 w2 = __builtin_shufflevector(w, w, 4, 5), w3 = __builtin_shufflevector(w, w, 6, 7);
    h2 x0 = __builtin_shufflevector(x, x, 0, 1), x1 = __builtin_shufflevector(x, x, 2, 3);
    h2 x2 = __builtin_shufflevector(x, x, 4, 5), x3 = __builtin_shufflevector(x, x, 6, 7);
    float acc = __builtin_amdgcn_fdot2(w0, x0, 0.0f, false);
    acc = __builtin_amdgcn_fdot2(w1, x1, acc, false);
    acc = __builtin_amdgcn_fdot2(w2, x2, acc, false);
    acc = __builtin_amdgcn_fdot2(w3, x3, acc, false);
    return acc;
}

// ---------------------------------------------------------------------------
// prep: W,X fp32 -> f16; zero S0/S1/S2 (contiguous).
// ---------------------------------------------------------------------------
__global__ __launch_bounds__(256) void prep_kernel(
    const float* __restrict__ X, const float* __restrict__ W,
    _Float16* __restrict__ Xh, _Float16* __restrict__ Wh,
    float* __restrict__ S)   // 3*NS floats
{
    const int g = blockIdx.x * 256 + threadIdx.x;
    const int stride = gridDim.x * 256;
    typedef _Float16 h4 __attribute__((ext_vector_type(4)));
    for (int k = g; k < NW / 4; k += stride) {
        const float4 f = ((const float4*)W)[k];
        h4 o = { (_Float16)f.x, (_Float16)f.y, (_Float16)f.z, (_Float16)f.w };
        ((h4*)Wh)[k] = o;
    }
    for (int k = g; k < NX / 4; k += stride) {
        const float4 f = ((const float4*)X)[k];
        h4 o = { (_Float16)f.x, (_Float16)f.y, (_Float16)f.z, (_Float16)f.w };
        ((h4*)Xh)[k] = o;
    }
    const float4 z = {0.f, 0.f, 0.f, 0.f};
    for (int k = g; k < 3 * NS / 4; k += stride) ((float4*)S)[k] = z;
}

// ---------------------------------------------------------------------------
// s0 via MFMA (verified): s0 = 0.1 * GEMM over K=(i,q)=9216.
// ---------------------------------------------------------------------------
__global__ __launch_bounds__(256) void s0_mfma_kernel(
    const _Float16* __restrict__ Xh, const _Float16* __restrict__ Wh,
    float* __restrict__ S0)
{
    const int wid  = blockIdx.x * 4 + (threadIdx.x >> 6);  // 0..1279
    const int lane = threadIdx.x & 63;
    const int bt  = wid / 80;
    const int rem = wid % 80;
    const int j   = rem >> 3;
    const int kc  = rem & 7;
    const int b0  = bt * 16;
    const int m    = lane & 15;
    const int quad = lane >> 4;
    const int ib   = kc * 144;

    const _Float16* ax = Xh + ((size_t)(b0 + m) * II + ib + quad) * QQ;
    const _Float16* bw = Wh + (((size_t)j * II + ib + quad) * PP + m) * QQ;

    f4 acc = {0.f, 0.f, 0.f, 0.f};
    for (int t = 0; t < 36; ++t) {
        const h8 a = *(const h8*)ax;
        const h8 b = *(const h8*)bw;
        acc = __builtin_amdgcn_mfma_f32_16x16x32_f16(a, b, acc, 0, 0, 0);
        ax += 4 * QQ;
        bw += (size_t)4 * PP * QQ;
    }
#pragma unroll
    for (int r = 0; r < 4; ++r)
        atomicAdd(&S0[((size_t)(b0 + quad * 4 + r) * JJ + j) * PP + m], 0.1f * acc[r]);
}

// ---------------------------------------------------------------------------
// vv_kernel: squash + logit-weight precompute.
//  MODE 0: v = squash(S);  V0raw = v;  VV = v * log2e      (after s0)
//  MODE 1: v = squash(S);  VV = (v + V0raw) * log2e        (after pass 1)
// idx = (b*J + j)*16 + p; lanes 0-15 = one (b,j) row -> DPP row_sum16.
// ---------------------------------------------------------------------------
template <int MODE>
__global__ __launch_bounds__(256) void vv_kernel(
    const float* __restrict__ S, float* __restrict__ V0raw,
    float* __restrict__ VV)
{
    const int idx = blockIdx.x * 256 + threadIdx.x;   // 0..NS-1
    const float s = S[idx];
    const float n2 = row_sum16(s * s);
    const float sc = n2 * __builtin_amdgcn_rcpf(1.0f + n2)
                        * __builtin_amdgcn_rsqf(n2 + 1e-7f);
    const float v = s * sc;
    if (MODE == 0) {
        V0raw[idx] = v;
        VV[idx] = v * LOG2E;
    } else {
        VV[idx] = (v + V0raw[idx]) * LOG2E;
    }
}

// ---------------------------------------------------------------------------
// Fused routing pass (R0 structure) + IKT-deep i-tile K-loop:
// each block processes IKT consecutive i-tiles, accumulating sacc across
// them, and flushes ONE atomic set (atomics/pass: 5.9M -> 1.97M).
// Grid 768 = 3 blocks/CU exactly. Hot loop per i is UNCHANGED from R0.
// ---------------------------------------------------------------------------
__global__ __launch_bounds__(256, 4) void pass_kernel(
    const _Float16* __restrict__ Xh,  // [B][I][Q] f16
    const _Float16* __restrict__ Wh,  // [J][I][P][Q] f16
    const float* __restrict__ VV,     // [B][J][P] = v * log2e
    float* __restrict__ Sout)         // [B][J][P] pre-zeroed accumulator
{
    __shared__ _Float16 ws[JJ * WTILE];  // 20 KB
    __shared__ _Float16 xs[BT * XRH];    // 2.25 KB

    const int bt  = blockIdx.x & (NBT - 1);
    const int itg = blockIdx.x >> 4;     // 0..NITG-1
    const int b0  = bt * BT;
    const int tid = threadIdx.x;

    const int b_l = tid >> 4;
    const int p   = tid & 15;
    const int b   = b0 + b_l;

    // precomputed vv (10 loads; 16-lane coalesced per (b,j) segment)
    float vv[JJ];
#pragma unroll
    for (int j = 0; j < JJ; ++j)
        vv[j] = VV[((size_t)b * JJ + j) * PP + p];

    float sacc[JJ];
#pragma unroll
    for (int j = 0; j < JJ; ++j) sacc[j] = 0.0f;

    const _Float16* wb = ws + p * QQ;    // single LDS base; imm offsets below
    const _Float16* xb = xs + b_l * XRH;

    for (int t = 0; t < IKT; ++t) {
        const int i0 = (itg * IKT + t) * IT;

        __syncthreads();   // all waves done reading previous tile

        // ---- stage W tile: 1280 h8 chunks, 5 per thread (coalesced 16B/lane)
        {
            const size_t jstride = (size_t)II * PP * QQ;
            const _Float16* wsrc = Wh + (size_t)i0 * PP * QQ;
#pragma unroll
            for (int k = 0; k < 5; ++k) {
                const int c = tid + k * 256;   // 0..1279
                const int j = c >> 7;          // 128 h8 chunks per j
                const int r = c & 127;
                *(h8*)(ws + j * WTILE + r * 8) = *(const h8*)(wsrc + j * jstride + r * 8);
            }
            if (tid < 128) {
                const int xb_ = tid >> 3;
                const int xr  = tid & 7;
                *(h8*)(xs + xb_ * XRH + xr * 8) =
                    *(const h8*)(Xh + ((size_t)(b0 + xb_) * II + i0) * QQ + xr * 8);
            }
        }
        __syncthreads();

#pragma unroll
        for (int i = 0; i < IT; ++i) {
            const h8 x8 = *(const h8*)(xb + i * QQ);

            float h[JJ];
#pragma unroll
            for (int j = 0; j < JJ; ++j)
                h[j] = dot8(*(const h8*)(wb + j * WTILE + i * PP * QQ), x8);

            // packed-f16 16-lane logit reduction, j-pairs (5 packs, 40 insts)
            float e[JJ];
#pragma unroll
            for (int jp = 0; jp < JJ; jp += 2) {
                const h2 pk = __builtin_bit_cast(h2,
                    __builtin_amdgcn_cvt_pkrtz(vv[jp] * h[jp],
                                               vv[jp + 1] * h[jp + 1]));
                const h2 r = row_sum16_pk(pk);
                e[jp]     = __builtin_amdgcn_exp2f((float)r.x);
                e[jp + 1] = __builtin_amdgcn_exp2f((float)r.y);
            }
            float a0 = (e[0] + e[1]) + (e[2] + e[3]);
            float a1 = (e[4] + e[5]) + (e[6] + e[7]);
            const float sum = (a0 + a1) + (e[8] + e[9]);
            const float inv = __builtin_amdgcn_rcpf(sum);
#pragma unroll
            for (int j = 0; j < JJ; ++j) sacc[j] += (e[j] * inv) * h[j];
        }
    }

#pragma unroll
    for (int j = 0; j < JJ; ++j)
        atomicAdd(&Sout[((size_t)b * JJ + j) * PP + p], sacc[j]);
}

// ---------------------------------------------------------------------------
// final output squash (fp32 precise)
// ---------------------------------------------------------------------------
__global__ __launch_bounds__(256) void squash_out_kernel(const float* __restrict__ S,
                                                         float* __restrict__ V)
{
    const int idx = blockIdx.x * blockDim.x + threadIdx.x;  // (b*J + j)
    if (idx >= BB * JJ) return;
    const float4* sp = (const float4*)(S + idx * PP);
    float4 a = sp[0], b4 = sp[1], c4 = sp[2], d4 = sp[3];
    float s2 = a.x * a.x + a.y * a.y + a.z * a.z + a.w * a.w +
               b4.x * b4.x + b4.y * b4.y + b4.z * b4.z + b4.w * b4.w +
               c4.x * c4.x + c4.y * c4.y + c4.z * c4.z + c4.w * c4.w +
               d4.x * d4.x + d4.y * d4.y + d4.z * d4.z + d4.w * d4.w;
    const float scale = s2 / (1.0f + s2) / sqrtf(s2 + 1e-7f);
    a.x *= scale; a.y *= scale; a.z *= scale; a.w *= scale;
    b4.x *= scale; b4.y *= scale; b4.z *= scale; b4.w *= scale;
    c4.x *= scale; c4.y *= scale; c4.z *= scale; c4.w *= scale;
    d4.x *= scale; d4.y *= scale; d4.z *= scale; d4.w *= scale;
    float4* vp = (float4*)(V + idx * PP);
    vp[0] = a; vp[1] = b4; vp[2] = c4; vp[3] = d4;
}

extern "C" void kernel_launch(void* const* d_in, const int* in_sizes, int n_in,
                              void* d_out, int out_size, void* d_ws, size_t ws_size,
                              hipStream_t stream)
{
    const float* X = (const float*)d_in[0];  // [256][1152][8]
    const float* W = (const float*)d_in[1];  // [10][1152][16][8]
    float* out = (float*)d_out;              // [256][10][16]

    _Float16* Xh = (_Float16*)d_ws;          // NX halfs
    _Float16* Wh = Xh + NX;                  // NW halfs
    float* S0 = (float*)(Wh + NW);           // NS floats
    float* S1 = S0 + NS;
    float* S2 = S1 + NS;
    float* V0raw = S2 + NS;                  // NS floats
    float* VV1   = V0raw + NS;               // NS floats
    float* VV2   = VV1 + NS;                 // NS floats; total ~8.6 MB

    const int grid  = NBT * NITG;            // 768 blocks of 256 threads
    const int vgrid = NS / 256;              // 160 blocks

    prep_kernel<<<1024, 256, 0, stream>>>(X, W, Xh, Wh, S0);
    s0_mfma_kernel<<<320, 256, 0, stream>>>(Xh, Wh, S0);
    vv_kernel<0><<<vgrid, 256, 0, stream>>>(S0, V0raw, VV1);
    pass_kernel<<<grid, 256, 0, stream>>>(Xh, Wh, VV1, S1);
    vv_kernel<1><<<vgrid, 256, 0, stream>>>(S1, V0raw, VV2);
    pass_kernel<<<grid, 256, 0, stream>>>(Xh, Wh, VV2, S2);
    squash_out_kernel<<<10, 256, 0, stream>>>(S2, out);
}

// Round 7
// 158.812 us; speedup vs baseline: 2.1458x; 1.3803x over previous
//
#include <hip/hip_runtime.h>

typedef _Float16 h2 __attribute__((ext_vector_type(2)));
typedef _Float16 h8 __attribute__((ext_vector_type(8)));
typedef float f4 __attribute__((ext_vector_type(4)));

#define BB 256
#define II 1152
#define QQ 8
#define JJ 10
#define PP 16

#define BT 16            // b per block (R0 config — best measured structure)
#define IT 8             // i per block
#define NBT (BB / BT)    // 16
#define NIT (II / IT)    // 144
#define XRH 72           // halfs per staged-x b-row (64 + 8 pad)
#define WTILE (IT * PP * QQ)     // 1024 halfs per j in the LDS W-tile

#define NW (JJ * II * PP * QQ)   // 1474560
#define NX (BB * II * QQ)        // 2359296
#define NS (BB * JJ * PP)        // 40960
#define BLK2 (JJ * BT * PP)      // 2560 floats per block partial
#define LOG2E 1.4426950408889634f

// ---------------------------------------------------------------------------
// 16-lane row sum via DPP — f32 and packed-f16 variants.
// ---------------------------------------------------------------------------
template <int CTRL>
__device__ __forceinline__ float dpp_add(float v) {
    int s = __builtin_bit_cast(int, v);
    int t = __builtin_amdgcn_update_dpp(0, s, CTRL, 0xF, 0xF, true);
    return v + __builtin_bit_cast(float, t);
}
__device__ __forceinline__ float row_sum16(float v) {
    v = dpp_add<0xB1>(v);   // xor1
    v = dpp_add<0x4E>(v);   // xor2
    v = dpp_add<0x124>(v);  // row_ror:4
    v = dpp_add<0x128>(v);  // row_ror:8
    return v;
}
template <int CTRL>
__device__ __forceinline__ h2 dpp_add_pk(h2 v) {
    int s = __builtin_bit_cast(int, v);
    int t = __builtin_amdgcn_update_dpp(0, s, CTRL, 0xF, 0xF, true);
    return v + __builtin_bit_cast(h2, t);   // v_pk_add_f16
}
__device__ __forceinline__ h2 row_sum16_pk(h2 v) {
    v = dpp_add_pk<0xB1>(v);
    v = dpp_add_pk<0x4E>(v);
    v = dpp_add_pk<0x124>(v);
    v = dpp_add_pk<0x128>(v);
    return v;
}

// 8-element f16 dot with fp32 accumulate: 4 x v_dot2_f32_f16.
__device__ __forceinline__ float dot8(h8 w, h8 x) {
    h2 w0 = __builtin_shufflevector(w, w, 0, 1), w1 = __builtin_shufflevector(w, w, 2, 3);
    h2 w2 = __builtin_shufflevector(w, w, 4, 5), w3 = __builtin_shufflevector(w, w, 6, 7);
    h2 x0 = __builtin_shufflevector(x, x, 0, 1), x1 = __builtin_shufflevector(x, x, 2, 3);
    h2 x2 = __builtin_shufflevector(x, x, 4, 5), x3 = __builtin_shufflevector(x, x, 6, 7);
    float acc = __builtin_amdgcn_fdot2(w0, x0, 0.0f, false);
    acc = __builtin_amdgcn_fdot2(w1, x1, acc, false);
    acc = __builtin_amdgcn_fdot2(w2, x2, acc, false);
    acc = __builtin_amdgcn_fdot2(w3, x3, acc, false);
    return acc;
}

// sum of 144 it-partials for output slot (b,j,p).
// Part layout: [it*16 + bt][j*256 + b_l*16 + p]
__device__ __forceinline__ float reduce_partials(const float* __restrict__ Part,
                                                 int idx) {
    const int b = idx / (JJ * PP);
    const int r = idx - b * (JJ * PP);        // j*16 + p
    const int bt  = b >> 4;
    const int pos = (r >> 4) * 256 + (b & 15) * 16 + (r & 15);
    const float* src = Part + (size_t)bt * BLK2 + pos;
    float s0 = 0.f, s1 = 0.f, s2 = 0.f, s3 = 0.f;
#pragma unroll 4
    for (int it = 0; it < NIT; it += 4) {
        s0 += src[(size_t)(it + 0) * (NBT * BLK2)];
        s1 += src[(size_t)(it + 1) * (NBT * BLK2)];
        s2 += src[(size_t)(it + 2) * (NBT * BLK2)];
        s3 += src[(size_t)(it + 3) * (NBT * BLK2)];
    }
    return (s0 + s1) + (s2 + s3);
}

// ---------------------------------------------------------------------------
// prep: W,X fp32 -> f16; zero S0 only (s0_mfma atomic target).
// ---------------------------------------------------------------------------
__global__ __launch_bounds__(256) void prep_kernel(
    const float* __restrict__ X, const float* __restrict__ W,
    _Float16* __restrict__ Xh, _Float16* __restrict__ Wh,
    float* __restrict__ S0)   // NS floats
{
    const int g = blockIdx.x * 256 + threadIdx.x;
    const int stride = gridDim.x * 256;
    typedef _Float16 h4 __attribute__((ext_vector_type(4)));
    for (int k = g; k < NW / 4; k += stride) {
        const float4 f = ((const float4*)W)[k];
        h4 o = { (_Float16)f.x, (_Float16)f.y, (_Float16)f.z, (_Float16)f.w };
        ((h4*)Wh)[k] = o;
    }
    for (int k = g; k < NX / 4; k += stride) {
        const float4 f = ((const float4*)X)[k];
        h4 o = { (_Float16)f.x, (_Float16)f.y, (_Float16)f.z, (_Float16)f.w };
        ((h4*)Xh)[k] = o;
    }
    const float4 z = {0.f, 0.f, 0.f, 0.f};
    for (int k = g; k < NS / 4; k += stride) ((float4*)S0)[k] = z;
}

// ---------------------------------------------------------------------------
// s0 via MFMA (verified): s0 = 0.1 * GEMM over K=(i,q)=9216.
// ---------------------------------------------------------------------------
__global__ __launch_bounds__(256) void s0_mfma_kernel(
    const _Float16* __restrict__ Xh, const _Float16* __restrict__ Wh,
    float* __restrict__ S0)
{
    const int wid  = blockIdx.x * 4 + (threadIdx.x >> 6);  // 0..1279
    const int lane = threadIdx.x & 63;
    const int bt  = wid / 80;
    const int rem = wid % 80;
    const int j   = rem >> 3;
    const int kc  = rem & 7;
    const int b0  = bt * 16;
    const int m    = lane & 15;
    const int quad = lane >> 4;
    const int ib   = kc * 144;

    const _Float16* ax = Xh + ((size_t)(b0 + m) * II + ib + quad) * QQ;
    const _Float16* bw = Wh + (((size_t)j * II + ib + quad) * PP + m) * QQ;

    f4 acc = {0.f, 0.f, 0.f, 0.f};
    for (int t = 0; t < 36; ++t) {
        const h8 a = *(const h8*)ax;
        const h8 b = *(const h8*)bw;
        acc = __builtin_amdgcn_mfma_f32_16x16x32_f16(a, b, acc, 0, 0, 0);
        ax += 4 * QQ;
        bw += (size_t)4 * PP * QQ;
    }
#pragma unroll
    for (int r = 0; r < 4; ++r)
        atomicAdd(&S0[((size_t)(b0 + quad * 4 + r) * JJ + j) * PP + m], 0.1f * acc[r]);
}

// ---------------------------------------------------------------------------
// vv_kernel MODE 0: v = squash(S0); V0raw = v; VV = v*log2e   (after s0)
// ---------------------------------------------------------------------------
__global__ __launch_bounds__(256) void vv0_kernel(
    const float* __restrict__ S, float* __restrict__ V0raw,
    float* __restrict__ VV)
{
    const int idx = blockIdx.x * 256 + threadIdx.x;   // 0..NS-1
    const float s = S[idx];
    const float n2 = row_sum16(s * s);
    const float sc = n2 * __builtin_amdgcn_rcpf(1.0f + n2)
                        * __builtin_amdgcn_rsqf(n2 + 1e-7f);
    const float v = s * sc;
    V0raw[idx] = v;
    VV[idx] = v * LOG2E;
}

// ---------------------------------------------------------------------------
// vvred_kernel (pass-1 epilogue): s1 = sum of partials; v = squash(s1);
// VV = (v + V0raw)*log2e.  Replaces global atomics + separate S1 buffer.
// ---------------------------------------------------------------------------
__global__ __launch_bounds__(256) void vvred_kernel(
    const float* __restrict__ Part, const float* __restrict__ V0raw,
    float* __restrict__ VV)
{
    const int idx = blockIdx.x * 256 + threadIdx.x;   // 0..NS-1
    const float s = reduce_partials(Part, idx);
    const float n2 = row_sum16(s * s);
    const float sc = n2 * __builtin_amdgcn_rcpf(1.0f + n2)
                        * __builtin_amdgcn_rsqf(n2 + 1e-7f);
    const float v = s * sc;
    VV[idx] = (v + V0raw[idx]) * LOG2E;
}

// ---------------------------------------------------------------------------
// Fused routing pass — EXACT R0 structure (132 µs baseline) except the
// epilogue: plain coalesced partial stores instead of global atomicAdd
// (R5 counters: device atomics cost ~128 B fabric RMW each — 252 MB/pass).
// ---------------------------------------------------------------------------
__global__ __launch_bounds__(256, 4) void pass_kernel(
    const _Float16* __restrict__ Xh,  // [B][I][Q] f16
    const _Float16* __restrict__ Wh,  // [J][I][P][Q] f16
    const float* __restrict__ VV,     // [B][J][P] = v * log2e
    float* __restrict__ Part)         // [2304][2560] partial sums
{
    __shared__ _Float16 ws[JJ * WTILE];  // 20 KB
    __shared__ _Float16 xs[BT * XRH];    // 2.25 KB

    const int bt = blockIdx.x & (NBT - 1);
    const int it = blockIdx.x >> 4;
    const int b0 = bt * BT;
    const int i0 = it * IT;
    const int tid = threadIdx.x;

    // ---- stage W tile: 1280 h8 chunks, 5 per thread (coalesced 16B/lane)
    {
        const size_t jstride = (size_t)II * PP * QQ;
        const _Float16* wsrc = Wh + (size_t)i0 * PP * QQ;
#pragma unroll
        for (int k = 0; k < 5; ++k) {
            const int c = tid + k * 256;   // 0..1279
            const int j = c >> 7;          // 128 h8 chunks per j
            const int r = c & 127;
            *(h8*)(ws + j * WTILE + r * 8) = *(const h8*)(wsrc + j * jstride + r * 8);
        }
        if (tid < 128) {
            const int xb = tid >> 3;
            const int xr = tid & 7;
            *(h8*)(xs + xb * XRH + xr * 8) =
                *(const h8*)(Xh + ((size_t)(b0 + xb) * II + i0) * QQ + xr * 8);
        }
    }
    __syncthreads();

    const int b_l = tid >> 4;
    const int p   = tid & 15;
    const int b   = b0 + b_l;

    // precomputed vv (10 loads; 16-lane coalesced per (b,j) segment)
    float vv[JJ];
#pragma unroll
    for (int j = 0; j < JJ; ++j)
        vv[j] = VV[((size_t)b * JJ + j) * PP + p];

    float sacc[JJ];
#pragma unroll
    for (int j = 0; j < JJ; ++j) sacc[j] = 0.0f;

    const _Float16* wb = ws + p * QQ;    // single LDS base; imm offsets below
    const _Float16* xb = xs + b_l * XRH;

#pragma unroll
    for (int i = 0; i < IT; ++i) {
        const h8 x8 = *(const h8*)(xb + i * QQ);

        float h[JJ];
#pragma unroll
        for (int j = 0; j < JJ; ++j)
            h[j] = dot8(*(const h8*)(wb + j * WTILE + i * PP * QQ), x8);

        // packed-f16 16-lane logit reduction, j-pairs (5 packs, 40 insts)
        float e[JJ];
#pragma unroll
        for (int jp = 0; jp < JJ; jp += 2) {
            const h2 pk = __builtin_bit_cast(h2,
                __builtin_amdgcn_cvt_pkrtz(vv[jp] * h[jp],
                                           vv[jp + 1] * h[jp + 1]));
            const h2 r = row_sum16_pk(pk);
            e[jp]     = __builtin_amdgcn_exp2f((float)r.x);
            e[jp + 1] = __builtin_amdgcn_exp2f((float)r.y);
        }
        float a0 = (e[0] + e[1]) + (e[2] + e[3]);
        float a1 = (e[4] + e[5]) + (e[6] + e[7]);
        const float sum = (a0 + a1) + (e[8] + e[9]);
        const float inv = __builtin_amdgcn_rcpf(sum);
#pragma unroll
        for (int j = 0; j < JJ; ++j) sacc[j] += (e[j] * inv) * h[j];
    }

    // ---- epilogue: plain streaming partial stores (coalesced, no atomics)
    float* dst = Part + (size_t)blockIdx.x * BLK2;
#pragma unroll
    for (int j = 0; j < JJ; ++j)
        dst[j * 256 + tid] = sacc[j];
}

// ---------------------------------------------------------------------------
// final output: reduce partials + squash (fp32 precise), one thread per
// (b,j,p); lanes 0-15 = one (b,j) row -> DPP row_sum16 for |s|^2.
// ---------------------------------------------------------------------------
__global__ __launch_bounds__(256) void squash_out_kernel(
    const float* __restrict__ Part, float* __restrict__ V)
{
    const int idx = blockIdx.x * 256 + threadIdx.x;   // 0..NS-1
    const float s = reduce_partials(Part, idx);
    const float n2 = row_sum16(s * s);
    const float scale = n2 / (1.0f + n2) / sqrtf(n2 + 1e-7f);
    V[idx] = s * scale;
}

extern "C" void kernel_launch(void* const* d_in, const int* in_sizes, int n_in,
                              void* d_out, int out_size, void* d_ws, size_t ws_size,
                              hipStream_t stream)
{
    const float* X = (const float*)d_in[0];  // [256][1152][8]
    const float* W = (const float*)d_in[1];  // [10][1152][16][8]
    float* out = (float*)d_out;              // [256][10][16]

    _Float16* Xh = (_Float16*)d_ws;          // NX halfs
    _Float16* Wh = Xh + NX;                  // NW halfs
    float* S0 = (float*)(Wh + NW);           // NS floats
    float* V0raw = S0 + NS;                  // NS floats
    float* VV1   = V0raw + NS;               // NS floats
    float* VV2   = VV1 + NS;                 // NS floats
    float* Part  = VV2 + NS;                 // 2304*2560 floats = 23.6 MB

    const int grid  = NBT * NIT;             // 2304 blocks of 256 threads
    const int vgrid = NS / 256;              // 160 blocks

    prep_kernel<<<1024, 256, 0, stream>>>(X, W, Xh, Wh, S0);
    s0_mfma_kernel<<<320, 256, 0, stream>>>(Xh, Wh, S0);
    vv0_kernel<<<vgrid, 256, 0, stream>>>(S0, V0raw, VV1);
    pass_kernel<<<grid, 256, 0, stream>>>(Xh, Wh, VV1, Part);
    vvred_kernel<<<vgrid, 256, 0, stream>>>(Part, V0raw, VV2);
    pass_kernel<<<grid, 256, 0, stream>>>(Xh, Wh, VV2, Part);
    squash_out_kernel<<<vgrid, 256, 0, stream>>>(Part, out);
}

// Round 8
// 148.268 us; speedup vs baseline: 2.2984x; 1.0711x over previous
//
#include <hip/hip_runtime.h>

typedef _Float16 h2 __attribute__((ext_vector_type(2)));
typedef _Float16 h8 __attribute__((ext_vector_type(8)));
typedef float f4 __attribute__((ext_vector_type(4)));

#define BB 256
#define II 1152
#define QQ 8
#define JJ 10
#define PP 16

#define BT 16            // b per block (R0 config — best measured structure)
#define IT 8             // i per block
#define NBT (BB / BT)    // 16
#define NIT (II / IT)    // 144
#define XRH 72           // halfs per staged-x b-row (64 + 8 pad)
#define WTILE (IT * PP * QQ)     // 1024 halfs per j in the LDS W-tile

#define NW (JJ * II * PP * QQ)   // 1474560
#define NX (BB * II * QQ)        // 2359296
#define NS (BB * JJ * PP)        // 40960
#define BLK2 (JJ * BT * PP)      // 2560 floats per block partial
#define RS 8                     // reduction split (slices of 144/RS=18)
#define LOG2E 1.4426950408889634f

// ---------------------------------------------------------------------------
// 16-lane row sum via DPP — f32 and packed-f16 variants.
// ---------------------------------------------------------------------------
template <int CTRL>
__device__ __forceinline__ float dpp_add(float v) {
    int s = __builtin_bit_cast(int, v);
    int t = __builtin_amdgcn_update_dpp(0, s, CTRL, 0xF, 0xF, true);
    return v + __builtin_bit_cast(float, t);
}
__device__ __forceinline__ float row_sum16(float v) {
    v = dpp_add<0xB1>(v);   // xor1
    v = dpp_add<0x4E>(v);   // xor2
    v = dpp_add<0x124>(v);  // row_ror:4
    v = dpp_add<0x128>(v);  // row_ror:8
    return v;
}
template <int CTRL>
__device__ __forceinline__ h2 dpp_add_pk(h2 v) {
    int s = __builtin_bit_cast(int, v);
    int t = __builtin_amdgcn_update_dpp(0, s, CTRL, 0xF, 0xF, true);
    return v + __builtin_bit_cast(h2, t);   // v_pk_add_f16
}
__device__ __forceinline__ h2 row_sum16_pk(h2 v) {
    v = dpp_add_pk<0xB1>(v);
    v = dpp_add_pk<0x4E>(v);
    v = dpp_add_pk<0x124>(v);
    v = dpp_add_pk<0x128>(v);
    return v;
}

// 8-element f16 dot with fp32 accumulate: 4 x v_dot2_f32_f16.
__device__ __forceinline__ float dot8(h8 w, h8 x) {
    h2 w0 = __builtin_shufflevector(w, w, 0, 1), w1 = __builtin_shufflevector(w, w, 2, 3);
    h2 w2 = __builtin_shufflevector(w, w, 4, 5), w3 = __builtin_shufflevector(w, w, 6, 7);
    h2 x0 = __builtin_shufflevector(x, x, 0, 1), x1 = __builtin_shufflevector(x, x, 2, 3);
    h2 x2 = __builtin_shufflevector(x, x, 4, 5), x3 = __builtin_shufflevector(x, x, 6, 7);
    float acc = __builtin_amdgcn_fdot2(w0, x0, 0.0f, false);
    acc = __builtin_amdgcn_fdot2(w1, x1, acc, false);
    acc = __builtin_amdgcn_fdot2(w2, x2, acc, false);
    acc = __builtin_amdgcn_fdot2(w3, x3, acc, false);
    return acc;
}

// slice-sum of 18 it-partials for output slot (b,j,p), slice in [0,8).
// Part layout: [it*16 + bt][j*256 + b_l*16 + p]
__device__ __forceinline__ float reduce_slice(const float* __restrict__ Part,
                                              int slot, int slice) {
    const int b = slot / (JJ * PP);
    const int r = slot - b * (JJ * PP);       // j*16 + p
    const int bt  = b >> 4;
    const int pos = (r >> 4) * 256 + (b & 15) * 16 + (r & 15);
    const float* src = Part + (size_t)bt * BLK2 + pos
                     + (size_t)(slice * (NIT / RS)) * (NBT * BLK2);
    float s0 = 0.f, s1 = 0.f;
#pragma unroll
    for (int it = 0; it < NIT / RS; it += 2) {
        s0 += src[(size_t)(it + 0) * (NBT * BLK2)];
        s1 += src[(size_t)(it + 1) * (NBT * BLK2)];
    }
    return s0 + s1;
}

// ---------------------------------------------------------------------------
// prep: W,X fp32 -> f16; zero S0 only (s0_mfma atomic target).
// ---------------------------------------------------------------------------
__global__ __launch_bounds__(256) void prep_kernel(
    const float* __restrict__ X, const float* __restrict__ W,
    _Float16* __restrict__ Xh, _Float16* __restrict__ Wh,
    float* __restrict__ S0)   // NS floats
{
    const int g = blockIdx.x * 256 + threadIdx.x;
    const int stride = gridDim.x * 256;
    typedef _Float16 h4 __attribute__((ext_vector_type(4)));
    for (int k = g; k < NW / 4; k += stride) {
        const float4 f = ((const float4*)W)[k];
        h4 o = { (_Float16)f.x, (_Float16)f.y, (_Float16)f.z, (_Float16)f.w };
        ((h4*)Wh)[k] = o;
    }
    for (int k = g; k < NX / 4; k += stride) {
        const float4 f = ((const float4*)X)[k];
        h4 o = { (_Float16)f.x, (_Float16)f.y, (_Float16)f.z, (_Float16)f.w };
        ((h4*)Xh)[k] = o;
    }
    const float4 z = {0.f, 0.f, 0.f, 0.f};
    for (int k = g; k < NS / 4; k += stride) ((float4*)S0)[k] = z;
}

// ---------------------------------------------------------------------------
// s0 via MFMA (verified): s0 = 0.1 * GEMM over K=(i,q)=9216.
// ---------------------------------------------------------------------------
__global__ __launch_bounds__(256) void s0_mfma_kernel(
    const _Float16* __restrict__ Xh, const _Float16* __restrict__ Wh,
    float* __restrict__ S0)
{
    const int wid  = blockIdx.x * 4 + (threadIdx.x >> 6);  // 0..1279
    const int lane = threadIdx.x & 63;
    const int bt  = wid / 80;
    const int rem = wid % 80;
    const int j   = rem >> 3;
    const int kc  = rem & 7;
    const int b0  = bt * 16;
    const int m    = lane & 15;
    const int quad = lane >> 4;
    const int ib   = kc * 144;

    const _Float16* ax = Xh + ((size_t)(b0 + m) * II + ib + quad) * QQ;
    const _Float16* bw = Wh + (((size_t)j * II + ib + quad) * PP + m) * QQ;

    f4 acc = {0.f, 0.f, 0.f, 0.f};
    for (int t = 0; t < 36; ++t) {
        const h8 a = *(const h8*)ax;
        const h8 b = *(const h8*)bw;
        acc = __builtin_amdgcn_mfma_f32_16x16x32_f16(a, b, acc, 0, 0, 0);
        ax += 4 * QQ;
        bw += (size_t)4 * PP * QQ;
    }
#pragma unroll
    for (int r = 0; r < 4; ++r)
        atomicAdd(&S0[((size_t)(b0 + quad * 4 + r) * JJ + j) * PP + m], 0.1f * acc[r]);
}

// ---------------------------------------------------------------------------
// vv0_kernel: v = squash(S0); V0raw = v; VV = v*log2e   (after s0)
// ---------------------------------------------------------------------------
__global__ __launch_bounds__(256) void vv0_kernel(
    const float* __restrict__ S, float* __restrict__ V0raw,
    float* __restrict__ VV)
{
    const int idx = blockIdx.x * 256 + threadIdx.x;   // 0..NS-1
    const float s = S[idx];
    const float n2 = row_sum16(s * s);
    const float sc = n2 * __builtin_amdgcn_rcpf(1.0f + n2)
                        * __builtin_amdgcn_rsqf(n2 + 1e-7f);
    const float v = s * sc;
    V0raw[idx] = v;
    VV[idx] = v * LOG2E;
}

// ---------------------------------------------------------------------------
// vvred_kernel (pass-1 epilogue), 8-way split reduction:
// grid 1280 x 256; 8 threads (in 8 waves) per output slot, 18 loads each,
// LDS combine, lanes 0-31 of wave 0 finish squash + VV store.
// R7 post-mortem: the monolithic 160-block reduce was latency-bound at
// 0.6 waves/SIMD (~22 us); this runs at 5 waves/SIMD with 18-deep chains.
// ---------------------------------------------------------------------------
__global__ __launch_bounds__(256) void vvred_kernel(
    const float* __restrict__ Part, const float* __restrict__ V0raw,
    float* __restrict__ VV)
{
    const int tid = threadIdx.x;
    const int slot = blockIdx.x * 32 + (tid & 31);
    const int slice = tid >> 5;                  // 0..7
    const float ps = reduce_slice(Part, slot, slice);

    __shared__ float red[256];
    red[tid] = ps;
    __syncthreads();
    if (tid < 32) {
        float s = 0.f;
#pragma unroll
        for (int k = 0; k < RS; ++k) s += red[tid + 32 * k];
        const float n2 = row_sum16(s * s);
        const float sc = n2 * __builtin_amdgcn_rcpf(1.0f + n2)
                            * __builtin_amdgcn_rsqf(n2 + 1e-7f);
        const float v = s * sc;
        VV[slot] = (v + V0raw[slot]) * LOG2E;
    }
}

// ---------------------------------------------------------------------------
// squash_out_kernel: same split reduction, fp32-precise squash, final out.
// ---------------------------------------------------------------------------
__global__ __launch_bounds__(256) void squash_out_kernel(
    const float* __restrict__ Part, float* __restrict__ V)
{
    const int tid = threadIdx.x;
    const int slot = blockIdx.x * 32 + (tid & 31);
    const int slice = tid >> 5;
    const float ps = reduce_slice(Part, slot, slice);

    __shared__ float red[256];
    red[tid] = ps;
    __syncthreads();
    if (tid < 32) {
        float s = 0.f;
#pragma unroll
        for (int k = 0; k < RS; ++k) s += red[tid + 32 * k];
        const float n2 = row_sum16(s * s);
        const float scale = n2 / (1.0f + n2) / sqrtf(n2 + 1e-7f);
        V[slot] = s * scale;
    }
}

// ---------------------------------------------------------------------------
// Fused routing pass — R0 hot loop (proven), atomic-free partial-store
// epilogue (R7: passes each dropped below 45 us with this).
// ---------------------------------------------------------------------------
__global__ __launch_bounds__(256, 4) void pass_kernel(
    const _Float16* __restrict__ Xh,  // [B][I][Q] f16
    const _Float16* __restrict__ Wh,  // [J][I][P][Q] f16
    const float* __restrict__ VV,     // [B][J][P] = v * log2e
    float* __restrict__ Part)         // [2304][2560] partial sums
{
    __shared__ _Float16 ws[JJ * WTILE];  // 20 KB
    __shared__ _Float16 xs[BT * XRH];    // 2.25 KB

    const int bt = blockIdx.x & (NBT - 1);
    const int it = blockIdx.x >> 4;
    const int b0 = bt * BT;
    const int i0 = it * IT;
    const int tid = threadIdx.x;

    // ---- stage W tile: 1280 h8 chunks, 5 per thread (coalesced 16B/lane)
    {
        const size_t jstride = (size_t)II * PP * QQ;
        const _Float16* wsrc = Wh + (size_t)i0 * PP * QQ;
#pragma unroll
        for (int k = 0; k < 5; ++k) {
            const int c = tid + k * 256;   // 0..1279
            const int j = c >> 7;          // 128 h8 chunks per j
            const int r = c & 127;
            *(h8*)(ws + j * WTILE + r * 8) = *(const h8*)(wsrc + j * jstride + r * 8);
        }
        if (tid < 128) {
            const int xb = tid >> 3;
            const int xr = tid & 7;
            *(h8*)(xs + xb * XRH + xr * 8) =
                *(const h8*)(Xh + ((size_t)(b0 + xb) * II + i0) * QQ + xr * 8);
        }
    }
    __syncthreads();

    const int b_l = tid >> 4;
    const int p   = tid & 15;
    const int b   = b0 + b_l;

    // precomputed vv (10 loads; 16-lane coalesced per (b,j) segment)
    float vv[JJ];
#pragma unroll
    for (int j = 0; j < JJ; ++j)
        vv[j] = VV[((size_t)b * JJ + j) * PP + p];

    float sacc[JJ];
#pragma unroll
    for (int j = 0; j < JJ; ++j) sacc[j] = 0.0f;

    const _Float16* wb = ws + p * QQ;    // single LDS base; imm offsets below
    const _Float16* xb = xs + b_l * XRH;

#pragma unroll
    for (int i = 0; i < IT; ++i) {
        const h8 x8 = *(const h8*)(xb + i * QQ);

        float h[JJ];
#pragma unroll
        for (int j = 0; j < JJ; ++j)
            h[j] = dot8(*(const h8*)(wb + j * WTILE + i * PP * QQ), x8);

        // packed-f16 16-lane logit reduction, j-pairs (5 packs, 40 insts)
        float e[JJ];
#pragma unroll
        for (int jp = 0; jp < JJ; jp += 2) {
            const h2 pk = __builtin_bit_cast(h2,
                __builtin_amdgcn_cvt_pkrtz(vv[jp] * h[jp],
                                           vv[jp + 1] * h[jp + 1]));
            const h2 r = row_sum16_pk(pk);
            e[jp]     = __builtin_amdgcn_exp2f((float)r.x);
            e[jp + 1] = __builtin_amdgcn_exp2f((float)r.y);
        }
        float a0 = (e[0] + e[1]) + (e[2] + e[3]);
        float a1 = (e[4] + e[5]) + (e[6] + e[7]);
        const float sum = (a0 + a1) + (e[8] + e[9]);
        const float inv = __builtin_amdgcn_rcpf(sum);
#pragma unroll
        for (int j = 0; j < JJ; ++j) sacc[j] += (e[j] * inv) * h[j];
    }

    // ---- epilogue: plain streaming partial stores (coalesced, no atomics)
    float* dst = Part + (size_t)blockIdx.x * BLK2;
#pragma unroll
    for (int j = 0; j < JJ; ++j)
        dst[j * 256 + tid] = sacc[j];
}

extern "C" void kernel_launch(void* const* d_in, const int* in_sizes, int n_in,
                              void* d_out, int out_size, void* d_ws, size_t ws_size,
                              hipStream_t stream)
{
    const float* X = (const float*)d_in[0];  // [256][1152][8]
    const float* W = (const float*)d_in[1];  // [10][1152][16][8]
    float* out = (float*)d_out;              // [256][10][16]

    _Float16* Xh = (_Float16*)d_ws;          // NX halfs
    _Float16* Wh = Xh + NX;                  // NW halfs
    float* S0 = (float*)(Wh + NW);           // NS floats
    float* V0raw = S0 + NS;                  // NS floats
    float* VV1   = V0raw + NS;               // NS floats
    float* VV2   = VV1 + NS;                 // NS floats
    float* Part  = VV2 + NS;                 // 2304*2560 floats = 23.6 MB

    const int grid  = NBT * NIT;             // 2304 blocks of 256 threads
    const int vgrid = NS / 256;              // 160 blocks
    const int rgrid = NS / 32;               // 1280 blocks (split reduce)

    prep_kernel<<<1024, 256, 0, stream>>>(X, W, Xh, Wh, S0);
    s0_mfma_kernel<<<320, 256, 0, stream>>>(Xh, Wh, S0);
    vv0_kernel<<<vgrid, 256, 0, stream>>>(S0, V0raw, VV1);
    pass_kernel<<<grid, 256, 0, stream>>>(Xh, Wh, VV1, Part);
    vvred_kernel<<<rgrid, 256, 0, stream>>>(Part, V0raw, VV2);
    pass_kernel<<<grid, 256, 0, stream>>>(Xh, Wh, VV2, Part);
    squash_out_kernel<<<rgrid, 256, 0, stream>>>(Part, out);
}

// Round 9
// 131.643 us; speedup vs baseline: 2.5886x; 1.1263x over previous
//
#include <hip/hip_runtime.h>

typedef _Float16 h2 __attribute__((ext_vector_type(2)));
typedef _Float16 h8 __attribute__((ext_vector_type(8)));
typedef float f4 __attribute__((ext_vector_type(4)));

#define BB 256
#define II 1152
#define QQ 8
#define JJ 10
#define PP 16

#define BT 16            // b per block (R0 config — best measured)
#define IT 8             // i per block
#define NBT (BB / BT)    // 16
#define NIT (II / IT)    // 144
#define XRH 72           // halfs per staged-x b-row (64 + 8 pad)
#define WTILE (IT * PP * QQ)     // 1024 halfs per j in the LDS W-tile

#define NW (JJ * II * PP * QQ)   // 1474560
#define NX (BB * II * QQ)        // 2359296
#define NS (BB * JJ * PP)        // 40960
#define LOG2E 1.4426950408889634f

// ---------------------------------------------------------------------------
// 16-lane row sum via DPP — f32 (for vv_kernel) and packed-f16 (hot loop).
// ---------------------------------------------------------------------------
template <int CTRL>
__device__ __forceinline__ float dpp_add(float v) {
    int s = __builtin_bit_cast(int, v);
    int t = __builtin_amdgcn_update_dpp(0, s, CTRL, 0xF, 0xF, true);
    return v + __builtin_bit_cast(float, t);
}
__device__ __forceinline__ float row_sum16(float v) {
    v = dpp_add<0xB1>(v);   // xor1
    v = dpp_add<0x4E>(v);   // xor2
    v = dpp_add<0x124>(v);  // row_ror:4
    v = dpp_add<0x128>(v);  // row_ror:8
    return v;
}
template <int CTRL>
__device__ __forceinline__ h2 dpp_add_pk(h2 v) {
    int s = __builtin_bit_cast(int, v);
    int t = __builtin_amdgcn_update_dpp(0, s, CTRL, 0xF, 0xF, true);
    return v + __builtin_bit_cast(h2, t);   // v_pk_add_f16
}
__device__ __forceinline__ h2 row_sum16_pk(h2 v) {
    v = dpp_add_pk<0xB1>(v);
    v = dpp_add_pk<0x4E>(v);
    v = dpp_add_pk<0x124>(v);
    v = dpp_add_pk<0x128>(v);
    return v;
}

// 8-element f16 dot with fp32 accumulate: 4 x v_dot2_f32_f16.
__device__ __forceinline__ float dot8(h8 w, h8 x) {
    h2 w0 = __builtin_shufflevector(w, w, 0, 1), w1 = __builtin_shufflevector(w, w, 2, 3);
    h2 w2 = __builtin_shufflevector(w, w, 4, 5), w3 = __builtin_shufflevector(w, w, 6, 7);
    h2 x0 = __builtin_shufflevector(x, x, 0, 1), x1 = __builtin_shufflevector(x, x, 2, 3);
    h2 x2 = __builtin_shufflevector(x, x, 4, 5), x3 = __builtin_shufflevector(x, x, 6, 7);
    float acc = __builtin_amdgcn_fdot2(w0, x0, 0.0f, false);
    acc = __builtin_amdgcn_fdot2(w1, x1, acc, false);
    acc = __builtin_amdgcn_fdot2(w2, x2, acc, false);
    acc = __builtin_amdgcn_fdot2(w3, x3, acc, false);
    return acc;
}

// ---------------------------------------------------------------------------
// prep: W,X fp32 -> f16 (natural Xh + transposed XT[i][b][q] for s0's
// A-operand coalescing); zero S0/S1/S2.
// ---------------------------------------------------------------------------
__global__ __launch_bounds__(256) void prep_kernel(
    const float* __restrict__ X, const float* __restrict__ W,
    _Float16* __restrict__ Xh, _Float16* __restrict__ Wh,
    _Float16* __restrict__ XT,
    float* __restrict__ S)   // 3*NS floats
{
    const int g = blockIdx.x * 256 + threadIdx.x;
    const int stride = gridDim.x * 256;
    typedef _Float16 h4 __attribute__((ext_vector_type(4)));
    for (int k = g; k < NW / 4; k += stride) {
        const float4 f = ((const float4*)W)[k];
        h4 o = { (_Float16)f.x, (_Float16)f.y, (_Float16)f.z, (_Float16)f.w };
        ((h4*)Wh)[k] = o;
    }
    for (int k = g; k < NX / 4; k += stride) {
        const float4 f = ((const float4*)X)[k];
        h4 o = { (_Float16)f.x, (_Float16)f.y, (_Float16)f.z, (_Float16)f.w };
        ((h4*)Xh)[k] = o;
        // transposed copy XT[(i*256 + b)*8 + q]
        const int e0 = k * 4;
        const int b  = e0 / (II * QQ);
        const int r  = e0 - b * (II * QQ);
        const int i  = r >> 3;
        const int q  = r & 7;
        *(h4*)(XT + ((size_t)i * BB + b) * QQ + q) = o;
    }
    const float4 z = {0.f, 0.f, 0.f, 0.f};
    for (int k = g; k < 3 * NS / 4; k += stride) ((float4*)S)[k] = z;
}

// ---------------------------------------------------------------------------
// s0 via MFMA: s0 = 0.1 * GEMM over K=(i,q)=9216.
// A-operand now reads XT[i][b][q] -> lane-contiguous (was a 64-line scatter).
// ---------------------------------------------------------------------------
__global__ __launch_bounds__(256) void s0_mfma_kernel(
    const _Float16* __restrict__ XT, const _Float16* __restrict__ Wh,
    float* __restrict__ S0)
{
    const int wid  = blockIdx.x * 4 + (threadIdx.x >> 6);  // 0..1279
    const int lane = threadIdx.x & 63;
    const int bt  = wid / 80;
    const int rem = wid % 80;
    const int j   = rem >> 3;
    const int kc  = rem & 7;
    const int b0  = bt * 16;
    const int m    = lane & 15;
    const int quad = lane >> 4;
    const int ib   = kc * 144;

    // A[m=b0+m][k=(i,q)]: XT[(ib+quad+4t)*256 + b0+m][0..8)
    const _Float16* ax = XT + ((size_t)(ib + quad) * BB + b0 + m) * QQ;
    const _Float16* bw = Wh + (((size_t)j * II + ib + quad) * PP + m) * QQ;

    f4 acc = {0.f, 0.f, 0.f, 0.f};
    for (int t = 0; t < 36; ++t) {
        const h8 a = *(const h8*)ax;
        const h8 b = *(const h8*)bw;
        acc = __builtin_amdgcn_mfma_f32_16x16x32_f16(a, b, acc, 0, 0, 0);
        ax += (size_t)4 * BB * QQ;
        bw += (size_t)4 * PP * QQ;
    }
#pragma unroll
    for (int r = 0; r < 4; ++r)
        atomicAdd(&S0[((size_t)(b0 + quad * 4 + r) * JJ + j) * PP + m], 0.1f * acc[r]);
}

// ---------------------------------------------------------------------------
// vv_kernel: squash + logit-weight precompute.
//  MODE 0: v = squash(S);  V0raw = v;  VV = v * log2e      (after s0)
//  MODE 1: v = squash(S);  VV = (v + V0raw) * log2e        (after pass 1)
// ---------------------------------------------------------------------------
template <int MODE>
__global__ __launch_bounds__(256) void vv_kernel(
    const float* __restrict__ S, float* __restrict__ V0raw,
    float* __restrict__ VV)
{
    const int idx = blockIdx.x * 256 + threadIdx.x;   // 0..NS-1
    const float s = S[idx];
    const float n2 = row_sum16(s * s);
    const float sc = n2 * __builtin_amdgcn_rcpf(1.0f + n2)
                        * __builtin_amdgcn_rsqf(n2 + 1e-7f);
    const float v = s * sc;
    if (MODE == 0) {
        V0raw[idx] = v;
        VV[idx] = v * LOG2E;
    } else {
        VV[idx] = (v + V0raw[idx]) * LOG2E;
    }
}

// ---------------------------------------------------------------------------
// Fused routing pass — EXACT R0 hot loop + atomic epilogue (132 us anchor),
// with two additions:
//  (a) XCD-bijective block swizzle: XCD x owns bt in {2x,2x+1} -> W (2.95MB)
//      + X slice (588KB) resident in that XCD's 4MB L2.
//  (b) vv pre-packed into 5 x h2; logit product = v_pk_mul_f16 (saves
//      5 VALU/i/thread and 5 VGPRs).
// ---------------------------------------------------------------------------
__global__ __launch_bounds__(256, 4) void pass_kernel(
    const _Float16* __restrict__ Xh,  // [B][I][Q] f16
    const _Float16* __restrict__ Wh,  // [J][I][P][Q] f16
    const float* __restrict__ VV,     // [B][J][P] = v * log2e
    float* __restrict__ Sout)         // [B][J][P] pre-zeroed accumulator
{
    __shared__ _Float16 ws[JJ * WTILE];  // 20 KB
    __shared__ _Float16 xs[BT * XRH];    // 2.25 KB

    // XCD-bijective swizzle (grid 2304 = 8 XCD * 288)
    const int L  = blockIdx.x;
    const int xc = L & 7;
    const int k8 = L >> 3;               // 0..287
    const int bt = 2 * xc + (k8 & 1);
    const int it = k8 >> 1;              // 0..143
    const int b0 = bt * BT;
    const int i0 = it * IT;
    const int tid = threadIdx.x;

    // ---- stage W tile: 1280 h8 chunks, 5 per thread (coalesced 16B/lane)
    {
        const size_t jstride = (size_t)II * PP * QQ;
        const _Float16* wsrc = Wh + (size_t)i0 * PP * QQ;
#pragma unroll
        for (int k = 0; k < 5; ++k) {
            const int c = tid + k * 256;   // 0..1279
            const int j = c >> 7;          // 128 h8 chunks per j
            const int r = c & 127;
            *(h8*)(ws + j * WTILE + r * 8) = *(const h8*)(wsrc + j * jstride + r * 8);
        }
        if (tid < 128) {
            const int xb = tid >> 3;
            const int xr = tid & 7;
            *(h8*)(xs + xb * XRH + xr * 8) =
                *(const h8*)(Xh + ((size_t)(b0 + xb) * II + i0) * QQ + xr * 8);
        }
    }
    __syncthreads();

    const int b_l = tid >> 4;
    const int p   = tid & 15;
    const int b   = b0 + b_l;

    // precomputed vv, packed once into 5 h2 (j-pairs)
    h2 vvpk[5];
#pragma unroll
    for (int jp = 0; jp < JJ; jp += 2) {
        const float v0 = VV[((size_t)b * JJ + jp) * PP + p];
        const float v1 = VV[((size_t)b * JJ + jp + 1) * PP + p];
        vvpk[jp >> 1] = __builtin_bit_cast(h2, __builtin_amdgcn_cvt_pkrtz(v0, v1));
    }

    float sacc[JJ];
#pragma unroll
    for (int j = 0; j < JJ; ++j) sacc[j] = 0.0f;

    const _Float16* wb = ws + p * QQ;    // single LDS base; imm offsets below
    const _Float16* xb = xs + b_l * XRH;

#pragma unroll
    for (int i = 0; i < IT; ++i) {
        const h8 x8 = *(const h8*)(xb + i * QQ);

        float h[JJ];
#pragma unroll
        for (int j = 0; j < JJ; ++j)
            h[j] = dot8(*(const h8*)(wb + j * WTILE + i * PP * QQ), x8);

        // packed-f16 16-lane logit reduction, j-pairs; product via pk_mul
        float e[JJ];
#pragma unroll
        for (int jp = 0; jp < JJ; jp += 2) {
            const h2 hp = __builtin_bit_cast(h2,
                __builtin_amdgcn_cvt_pkrtz(h[jp], h[jp + 1]));
            const h2 r = row_sum16_pk(vvpk[jp >> 1] * hp);
            e[jp]     = __builtin_amdgcn_exp2f((float)r.x);
            e[jp + 1] = __builtin_amdgcn_exp2f((float)r.y);
        }
        float a0 = (e[0] + e[1]) + (e[2] + e[3]);
        float a1 = (e[4] + e[5]) + (e[6] + e[7]);
        const float sum = (a0 + a1) + (e[8] + e[9]);
        const float inv = __builtin_amdgcn_rcpf(sum);
#pragma unroll
        for (int j = 0; j < JJ; ++j) sacc[j] += (e[j] * inv) * h[j];
    }

#pragma unroll
    for (int j = 0; j < JJ; ++j)
        atomicAdd(&Sout[((size_t)b * JJ + j) * PP + p], sacc[j]);
}

// ---------------------------------------------------------------------------
// final output squash (fp32 precise)
// ---------------------------------------------------------------------------
__global__ __launch_bounds__(256) void squash_out_kernel(const float* __restrict__ S,
                                                         float* __restrict__ V)
{
    const int idx = blockIdx.x * blockDim.x + threadIdx.x;  // (b*J + j)
    if (idx >= BB * JJ) return;
    const float4* sp = (const float4*)(S + idx * PP);
    float4 a = sp[0], b4 = sp[1], c4 = sp[2], d4 = sp[3];
    float s2 = a.x * a.x + a.y * a.y + a.z * a.z + a.w * a.w +
               b4.x * b4.x + b4.y * b4.y + b4.z * b4.z + b4.w * b4.w +
               c4.x * c4.x + c4.y * c4.y + c4.z * c4.z + c4.w * c4.w +
               d4.x * d4.x + d4.y * d4.y + d4.z * d4.z + d4.w * d4.w;
    const float scale = s2 / (1.0f + s2) / sqrtf(s2 + 1e-7f);
    a.x *= scale; a.y *= scale; a.z *= scale; a.w *= scale;
    b4.x *= scale; b4.y *= scale; b4.z *= scale; b4.w *= scale;
    c4.x *= scale; c4.y *= scale; c4.z *= scale; c4.w *= scale;
    d4.x *= scale; d4.y *= scale; d4.z *= scale; d4.w *= scale;
    float4* vp = (float4*)(V + idx * PP);
    vp[0] = a; vp[1] = b4; vp[2] = c4; vp[3] = d4;
}

extern "C" void kernel_launch(void* const* d_in, const int* in_sizes, int n_in,
                              void* d_out, int out_size, void* d_ws, size_t ws_size,
                              hipStream_t stream)
{
    const float* X = (const float*)d_in[0];  // [256][1152][8]
    const float* W = (const float*)d_in[1];  // [10][1152][16][8]
    float* out = (float*)d_out;              // [256][10][16]

    _Float16* Xh = (_Float16*)d_ws;          // NX halfs
    _Float16* Wh = Xh + NX;                  // NW halfs
    _Float16* XT = Wh + NW;                  // NX halfs (transposed X for s0)
    float* S0 = (float*)(XT + NX);           // NS floats
    float* S1 = S0 + NS;
    float* S2 = S1 + NS;
    float* V0raw = S2 + NS;                  // NS floats
    float* VV1   = V0raw + NS;               // NS floats
    float* VV2   = VV1 + NS;                 // NS floats; total ~13.3 MB

    const int grid  = NBT * NIT;             // 2304 blocks of 256 threads
    const int vgrid = NS / 256;              // 160 blocks

    prep_kernel<<<1024, 256, 0, stream>>>(X, W, Xh, Wh, XT, S0);
    s0_mfma_kernel<<<320, 256, 0, stream>>>(XT, Wh, S0);
    vv_kernel<0><<<vgrid, 256, 0, stream>>>(S0, V0raw, VV1);
    pass_kernel<<<grid, 256, 0, stream>>>(Xh, Wh, VV1, S1);
    vv_kernel<1><<<vgrid, 256, 0, stream>>>(S1, V0raw, VV2);
    pass_kernel<<<grid, 256, 0, stream>>>(Xh, Wh, VV2, S2);
    squash_out_kernel<<<10, 256, 0, stream>>>(S2, out);
}